// Round 1
// baseline (4523.460 us; speedup 1.0000x reference)
//
#include <hip/hip_runtime.h>

// GCN 2-layer: N=200000 nodes, E=12800000 edges, features 2 -> 16 -> 2.
// out = GCNConv2(relu(GCNConv1(x)))
// GCNConv(x,W,b): h = xW; deg = indegree(dst)+1; dinv = rsqrt(deg);
//   out[i] = dinv[i] * ( sum_{j->i} dinv[j]*h[j]  +  dinv[i]*h[i] ) + b
// We store g = dinv*h so edge work is a pure unweighted scatter-sum.

constexpr int N_NODES = 200000;
constexpr int N_EDGES = 12800000;
constexpr int F1 = 16;

__global__ __launch_bounds__(256) void deg_kernel(const int* __restrict__ dst,
                                                  float* __restrict__ deg) {
    int e = blockIdx.x * 256 + threadIdx.x;
    if (e < N_EDGES) atomicAdd(&deg[dst[e]], 1.0f);
}

__global__ __launch_bounds__(256) void node1_kernel(const float* __restrict__ x,
                                                    const float* __restrict__ W1,
                                                    const float* __restrict__ deg,
                                                    float* __restrict__ dinv,
                                                    float* __restrict__ g1) {
    int i = blockIdx.x * 256 + threadIdx.x;
    if (i >= N_NODES) return;
    float d = deg[i] + 1.0f;          // +1 self loop
    float di = rsqrtf(d);
    dinv[i] = di;
    float x0 = x[2 * i], x1 = x[2 * i + 1];
    float4 o[4];
#pragma unroll
    for (int f = 0; f < F1; f++) {
        float h = x0 * W1[f] + x1 * W1[F1 + f];   // W1 is (2,16) row-major
        ((float*)o)[f] = di * h;
    }
    float4* gp = (float4*)(g1 + (size_t)F1 * i);
    gp[0] = o[0]; gp[1] = o[1]; gp[2] = o[2]; gp[3] = o[3];
}

// 4 threads per edge, each handles a float4 feature chunk.
__global__ __launch_bounds__(256) void edge1_kernel(const int* __restrict__ src,
                                                    const int* __restrict__ dst,
                                                    const float* __restrict__ g1,
                                                    float* __restrict__ S1) {
    unsigned t = blockIdx.x * 256u + threadIdx.x;
    if (t >= (unsigned)N_EDGES * 4u) return;
    unsigned e = t >> 2;
    unsigned fb = (t & 3u) << 2;
    int s = src[e], d = dst[e];
    float4 v = *(const float4*)(g1 + (size_t)F1 * s + fb);
    float* p = S1 + (size_t)F1 * d + fb;
    atomicAdd(p + 0, v.x);
    atomicAdd(p + 1, v.y);
    atomicAdd(p + 2, v.z);
    atomicAdd(p + 3, v.w);
}

__global__ __launch_bounds__(256) void node2_kernel(const float* __restrict__ g1,
                                                    const float* __restrict__ S1,
                                                    const float* __restrict__ b1,
                                                    const float* __restrict__ W2,
                                                    const float* __restrict__ dinv,
                                                    float* __restrict__ g2) {
    int i = blockIdx.x * 256 + threadIdx.x;
    if (i >= N_NODES) return;
    float di = dinv[i];
    float acc0 = 0.f, acc1 = 0.f;
    const float4* Sp = (const float4*)(S1 + (size_t)F1 * i);
    const float4* Gp = (const float4*)(g1 + (size_t)F1 * i);
#pragma unroll
    for (int q = 0; q < 4; q++) {
        float4 s4 = Sp[q];
        float4 g4 = Gp[q];
        float vs[4] = {s4.x + g4.x, s4.y + g4.y, s4.z + g4.z, s4.w + g4.w};
#pragma unroll
        for (int j = 0; j < 4; j++) {
            int f = q * 4 + j;
            float o = di * vs[j] + b1[f];
            o = fmaxf(o, 0.f);                 // relu
            acc0 += o * W2[2 * f];             // W2 is (16,2) row-major
            acc1 += o * W2[2 * f + 1];
        }
    }
    g2[2 * i]     = di * acc0;
    g2[2 * i + 1] = di * acc1;
}

__global__ __launch_bounds__(256) void edge2_kernel(const int* __restrict__ src,
                                                    const int* __restrict__ dst,
                                                    const float* __restrict__ g2,
                                                    float* __restrict__ S2) {
    int e = blockIdx.x * 256 + threadIdx.x;
    if (e >= N_EDGES) return;
    int s = src[e], d = dst[e];
    float2 v = *(const float2*)(g2 + 2 * (size_t)s);
    atomicAdd(&S2[2 * (size_t)d], v.x);
    atomicAdd(&S2[2 * (size_t)d + 1], v.y);
}

__global__ __launch_bounds__(256) void node3_kernel(const float* __restrict__ g2,
                                                    const float* __restrict__ S2,
                                                    const float* __restrict__ b2,
                                                    const float* __restrict__ dinv,
                                                    float* __restrict__ out) {
    int i = blockIdx.x * 256 + threadIdx.x;
    if (i >= N_NODES) return;
    float di = dinv[i];
    out[2 * i]     = di * (S2[2 * i]     + g2[2 * i])     + b2[0];
    out[2 * i + 1] = di * (S2[2 * i + 1] + g2[2 * i + 1]) + b2[1];
}

extern "C" void kernel_launch(void* const* d_in, const int* in_sizes, int n_in,
                              void* d_out, int out_size, void* d_ws, size_t ws_size,
                              hipStream_t stream) {
    const float* x  = (const float*)d_in[0];
    const float* W1 = (const float*)d_in[1];
    const float* b1 = (const float*)d_in[2];
    const float* W2 = (const float*)d_in[3];
    const float* b2 = (const float*)d_in[4];
    const int* ei   = (const int*)d_in[5];   // (2, E): row 0 = src, row 1 = dst
    const int* src = ei;
    const int* dst = ei + N_EDGES;
    float* out = (float*)d_out;

    float* ws  = (float*)d_ws;
    float* deg  = ws;                              // N
    float* dinv = deg + N_NODES;                   // N
    float* g1   = dinv + N_NODES;                  // 16N
    float* S1   = g1 + (size_t)F1 * N_NODES;       // 16N
    float* g2   = S1 + (size_t)F1 * N_NODES;       // 2N
    float* S2   = g2 + 2 * (size_t)N_NODES;        // 2N  -> total 38N floats ~= 30.4 MB

    hipMemsetAsync(deg, 0, (size_t)N_NODES * sizeof(float), stream);
    hipMemsetAsync(S1, 0, (size_t)F1 * N_NODES * sizeof(float), stream);
    hipMemsetAsync(S2, 0, 2 * (size_t)N_NODES * sizeof(float), stream);

    deg_kernel<<<(N_EDGES + 255) / 256, 256, 0, stream>>>(dst, deg);
    node1_kernel<<<(N_NODES + 255) / 256, 256, 0, stream>>>(x, W1, deg, dinv, g1);
    edge1_kernel<<<(N_EDGES * 4 + 255) / 256, 256, 0, stream>>>(src, dst, g1, S1);
    node2_kernel<<<(N_NODES + 255) / 256, 256, 0, stream>>>(g1, S1, b1, W2, dinv, g2);
    edge2_kernel<<<(N_EDGES + 255) / 256, 256, 0, stream>>>(src, dst, g2, S2);
    node3_kernel<<<(N_NODES + 255) / 256, 256, 0, stream>>>(g2, S2, b2, dinv, out);
}

// Round 2
// 3124.997 us; speedup vs baseline: 1.4475x; 1.4475x over previous
//
#include <hip/hip_runtime.h>

// GCN 2-layer: N=200000, E=12800000, features 2 -> 16 -> 2.
// Rank trick: layer-1 aggregation done on the 2-dim input (before W1),
// layer-2 aggregation on the 2-dim output (after W2). Both edge passes
// scatter only float2 -> 64M total f32/int atomics instead of 230M.
//
// GCNConv(x,W,b): deg_i = indeg(dst)+1; dinv=rsqrt(deg);
//   out_i = dinv_i*( sum_{j->i} dinv_j*h_j + dinv_i*h_i ) + b,  h = xW
// Layer1: u_j = dinv_j*x_j (2-vec); A1_i = sum u_j; c_i = dinv_i*(A1_i+u_i);
//   out1 = c@W1 + b1 -> relu -> h2 = out1@W2; g2 = dinv*h2 (2-vec)
// Layer2: A2_i = sum g2_j; out = dinv_i*(A2_i+g2_i) + b2

constexpr int N_NODES = 200000;
constexpr int N_EDGES = 12800000;

__global__ __launch_bounds__(256) void deg_kernel(const int* __restrict__ dst,
                                                  int* __restrict__ degi) {
    int e = blockIdx.x * 256 + threadIdx.x;
    if (e < N_EDGES) atomicAdd(&degi[dst[e]], 1);
}

__global__ __launch_bounds__(256) void node1_kernel(const float* __restrict__ x,
                                                    const int* __restrict__ degi,
                                                    float* __restrict__ dinv,
                                                    float2* __restrict__ u) {
    int i = blockIdx.x * 256 + threadIdx.x;
    if (i >= N_NODES) return;
    float d = (float)(degi[i] + 1);        // +1 self loop
    float di = rsqrtf(d);
    dinv[i] = di;
    float2 xi = ((const float2*)x)[i];
    u[i] = make_float2(di * xi.x, di * xi.y);
}

// One thread per edge: scatter float2 table[src] into acc[dst].
__global__ __launch_bounds__(256) void agg_kernel(const int* __restrict__ src,
                                                  const int* __restrict__ dst,
                                                  const float2* __restrict__ table,
                                                  float* __restrict__ acc) {
    int e = blockIdx.x * 256 + threadIdx.x;
    if (e >= N_EDGES) return;
    int s = src[e], d = dst[e];
    float2 v = table[s];
    unsafeAtomicAdd(&acc[2 * (size_t)d], v.x);
    unsafeAtomicAdd(&acc[2 * (size_t)d + 1], v.y);
}

__global__ __launch_bounds__(256) void node2_kernel(const float2* __restrict__ u,
                                                    const float2* __restrict__ A1,
                                                    const float* __restrict__ W1,
                                                    const float* __restrict__ b1,
                                                    const float* __restrict__ W2,
                                                    const float* __restrict__ dinv,
                                                    float2* __restrict__ g2) {
    int i = blockIdx.x * 256 + threadIdx.x;
    if (i >= N_NODES) return;
    float di = dinv[i];
    float2 a = A1[i];
    float2 uu = u[i];
    float c0 = di * (a.x + uu.x);
    float c1 = di * (a.y + uu.y);
    float acc0 = 0.f, acc1 = 0.f;
#pragma unroll
    for (int f = 0; f < 16; f++) {
        float o = c0 * W1[f] + c1 * W1[16 + f] + b1[f];  // W1 (2,16) row-major
        o = fmaxf(o, 0.f);                               // relu
        acc0 += o * W2[2 * f];                           // W2 (16,2) row-major
        acc1 += o * W2[2 * f + 1];
    }
    g2[i] = make_float2(di * acc0, di * acc1);
}

__global__ __launch_bounds__(256) void node3_kernel(const float2* __restrict__ g2,
                                                    const float2* __restrict__ A2,
                                                    const float* __restrict__ b2,
                                                    const float* __restrict__ dinv,
                                                    float2* __restrict__ out) {
    int i = blockIdx.x * 256 + threadIdx.x;
    if (i >= N_NODES) return;
    float di = dinv[i];
    float2 a = A2[i];
    float2 g = g2[i];
    out[i] = make_float2(di * (a.x + g.x) + b2[0],
                         di * (a.y + g.y) + b2[1]);
}

extern "C" void kernel_launch(void* const* d_in, const int* in_sizes, int n_in,
                              void* d_out, int out_size, void* d_ws, size_t ws_size,
                              hipStream_t stream) {
    const float* x  = (const float*)d_in[0];
    const float* W1 = (const float*)d_in[1];
    const float* b1 = (const float*)d_in[2];
    const float* W2 = (const float*)d_in[3];
    const float* b2 = (const float*)d_in[4];
    const int* ei   = (const int*)d_in[5];   // (2,E): row 0 = src, row 1 = dst
    const int* src = ei;
    const int* dst = ei + N_EDGES;
    float2* out = (float2*)d_out;

    // Workspace layout (floats). Zeroed region first so one memset covers it.
    float* ws = (float*)d_ws;
    int*   degi = (int*)ws;                       // N      (zeroed)
    float* A1   = ws + N_NODES;                   // 2N     (zeroed)
    float* A2   = A1 + 2 * (size_t)N_NODES;       // 2N     (zeroed)
    float* dinv = A2 + 2 * (size_t)N_NODES;       // N
    float2* u   = (float2*)(dinv + N_NODES);      // 2N
    float2* g2  = u + N_NODES;                    // 2N  -> total 10N floats = 8 MB

    hipMemsetAsync(degi, 0, 5 * (size_t)N_NODES * sizeof(float), stream);

    constexpr int EB = (N_EDGES + 255) / 256;
    constexpr int NB = (N_NODES + 255) / 256;
    deg_kernel<<<EB, 256, 0, stream>>>(dst, degi);
    node1_kernel<<<NB, 256, 0, stream>>>(x, degi, dinv, u);
    agg_kernel<<<EB, 256, 0, stream>>>(src, dst, u, A1);
    node2_kernel<<<NB, 256, 0, stream>>>(u, (const float2*)A1, W1, b1, W2, dinv, g2);
    agg_kernel<<<EB, 256, 0, stream>>>(src, dst, g2, A2);
    node3_kernel<<<NB, 256, 0, stream>>>(g2, (const float2*)A2, b2, dinv, out);
}

// Round 3
// 3090.816 us; speedup vs baseline: 1.4635x; 1.0111x over previous
//
#include <hip/hip_runtime.h>

// GCN 2-layer: N=200000, E=12800000, features 2 -> 16 -> 2.
// Rank trick (R2): aggregate 2-dim vectors only (before W1 / after W2).
// R3: per-XCD privatized accumulators + workgroup-scope atomics.
//   Agent-scope atomics on gfx950 write through to the memory-side coherent
//   point (~20 G transactions/s observed, 31 B/atomic WRITE_SIZE). By giving
//   each XCD a private replica (indexed via s_getreg(HW_REG_XCC_ID)), all
//   writers of a replica share one TCC, so workgroup-scope (no sc1) atomics
//   legally execute on the L2-resident line. End-of-kernel L2 writeback makes
//   replicas visible to the merge kernels.

constexpr int N_NODES = 200000;
constexpr int N_EDGES = 12800000;
constexpr int NREP = 8;   // 8 XCDs [measured m09]

__device__ __forceinline__ unsigned xcc_id() {
    // s_getreg_b32: id=20 (HW_REG_XCC_ID), offset=0, width=4
    return __builtin_amdgcn_s_getreg((3u << 11) | (0u << 6) | 20u) & 7u;
}

__global__ __launch_bounds__(256) void deg_kernel(const int* __restrict__ dst,
                                                  int* __restrict__ degR) {
    int e = blockIdx.x * 256 + threadIdx.x;
    if (e >= N_EDGES) return;
    int* deg = degR + (size_t)xcc_id() * N_NODES;
    __hip_atomic_fetch_add(&deg[dst[e]], 1, __ATOMIC_RELAXED,
                           __HIP_MEMORY_SCOPE_WORKGROUP);
}

__global__ __launch_bounds__(256) void node1_kernel(const float* __restrict__ x,
                                                    const int* __restrict__ degR,
                                                    float* __restrict__ dinv,
                                                    float2* __restrict__ u) {
    int i = blockIdx.x * 256 + threadIdx.x;
    if (i >= N_NODES) return;
    int d = 1;  // +1 self loop
#pragma unroll
    for (int k = 0; k < NREP; k++) d += degR[(size_t)k * N_NODES + i];
    float di = rsqrtf((float)d);
    dinv[i] = di;
    float2 xi = ((const float2*)x)[i];
    u[i] = make_float2(di * xi.x, di * xi.y);
}

// One thread per edge: scatter float2 table[src] into this XCD's replica.
__global__ __launch_bounds__(256) void agg_kernel(const int* __restrict__ src,
                                                  const int* __restrict__ dst,
                                                  const float2* __restrict__ table,
                                                  float* __restrict__ accR) {
    int e = blockIdx.x * 256 + threadIdx.x;
    if (e >= N_EDGES) return;
    float* acc = accR + (size_t)xcc_id() * (2 * (size_t)N_NODES);
    int s = src[e], d = dst[e];
    float2 v = table[s];
    __hip_atomic_fetch_add(&acc[2 * (size_t)d], v.x, __ATOMIC_RELAXED,
                           __HIP_MEMORY_SCOPE_WORKGROUP);
    __hip_atomic_fetch_add(&acc[2 * (size_t)d + 1], v.y, __ATOMIC_RELAXED,
                           __HIP_MEMORY_SCOPE_WORKGROUP);
}

__global__ __launch_bounds__(256) void node2_kernel(const float2* __restrict__ u,
                                                    const float* __restrict__ accR,
                                                    const float* __restrict__ W1,
                                                    const float* __restrict__ b1,
                                                    const float* __restrict__ W2,
                                                    const float* __restrict__ dinv,
                                                    float2* __restrict__ g2) {
    int i = blockIdx.x * 256 + threadIdx.x;
    if (i >= N_NODES) return;
    float ax = 0.f, ay = 0.f;
#pragma unroll
    for (int k = 0; k < NREP; k++) {
        const float2 a = ((const float2*)(accR + (size_t)k * (2 * (size_t)N_NODES)))[i];
        ax += a.x; ay += a.y;
    }
    float di = dinv[i];
    float2 uu = u[i];
    float c0 = di * (ax + uu.x);
    float c1 = di * (ay + uu.y);
    float acc0 = 0.f, acc1 = 0.f;
#pragma unroll
    for (int f = 0; f < 16; f++) {
        float o = c0 * W1[f] + c1 * W1[16 + f] + b1[f];  // W1 (2,16) row-major
        o = fmaxf(o, 0.f);                               // relu
        acc0 += o * W2[2 * f];                           // W2 (16,2) row-major
        acc1 += o * W2[2 * f + 1];
    }
    g2[i] = make_float2(di * acc0, di * acc1);
}

__global__ __launch_bounds__(256) void node3_kernel(const float2* __restrict__ g2,
                                                    const float* __restrict__ accR,
                                                    const float* __restrict__ b2,
                                                    const float* __restrict__ dinv,
                                                    float2* __restrict__ out) {
    int i = blockIdx.x * 256 + threadIdx.x;
    if (i >= N_NODES) return;
    float ax = 0.f, ay = 0.f;
#pragma unroll
    for (int k = 0; k < NREP; k++) {
        const float2 a = ((const float2*)(accR + (size_t)k * (2 * (size_t)N_NODES)))[i];
        ax += a.x; ay += a.y;
    }
    float di = dinv[i];
    float2 g = g2[i];
    out[i] = make_float2(di * (ax + g.x) + b2[0],
                         di * (ay + g.y) + b2[1]);
}

extern "C" void kernel_launch(void* const* d_in, const int* in_sizes, int n_in,
                              void* d_out, int out_size, void* d_ws, size_t ws_size,
                              hipStream_t stream) {
    const float* x  = (const float*)d_in[0];
    const float* W1 = (const float*)d_in[1];
    const float* b1 = (const float*)d_in[2];
    const float* W2 = (const float*)d_in[3];
    const float* b2 = (const float*)d_in[4];
    const int* ei   = (const int*)d_in[5];   // (2,E): row 0 = src, row 1 = dst
    const int* src = ei;
    const int* dst = ei + N_EDGES;
    float2* out = (float2*)d_out;

    // Workspace (floats/ints, 4B units):
    //   degR:  8N ints   (zeroed)   [0, 8N)
    //   accR: 16N floats (zeroed)   [8N, 24N)   -- reused for both layers
    //   dinv:  N                    [24N, 25N)
    //   u:    2N                    [25N, 27N)
    //   g2:   2N                    [27N, 29N)   total 29N*4B = 23.2 MB
    float* ws = (float*)d_ws;
    int*   degR = (int*)ws;
    float* accR = ws + (size_t)NREP * N_NODES;
    float* dinv = accR + (size_t)NREP * 2 * N_NODES;
    float2* u   = (float2*)(dinv + N_NODES);
    float2* g2  = u + N_NODES;

    constexpr int EB = (N_EDGES + 255) / 256;
    constexpr int NB = (N_NODES + 255) / 256;
    const size_t accR_bytes = (size_t)NREP * 2 * N_NODES * sizeof(float);

    hipMemsetAsync(degR, 0, (size_t)NREP * N_NODES * sizeof(int) + accR_bytes, stream);
    deg_kernel<<<EB, 256, 0, stream>>>(dst, degR);
    node1_kernel<<<NB, 256, 0, stream>>>(x, degR, dinv, u);
    agg_kernel<<<EB, 256, 0, stream>>>(src, dst, u, accR);
    node2_kernel<<<NB, 256, 0, stream>>>(u, accR, W1, b1, W2, dinv, g2);
    hipMemsetAsync(accR, 0, accR_bytes, stream);      // re-zero for layer 2
    agg_kernel<<<EB, 256, 0, stream>>>(src, dst, g2, accR);
    node3_kernel<<<NB, 256, 0, stream>>>(g2, accR, b2, dinv, out);
}

// Round 4
// 790.574 us; speedup vs baseline: 5.7217x; 3.9096x over previous
//
#include <hip/hip_runtime.h>

// GCN 2-layer: N=200000, E=12800000, features 2 -> 16 -> 2.
// R2 rank trick: aggregate only 2-dim vectors (before W1 / after W2).
// R4: global atomics (measured hard ceiling ~20G line-transactions/s on
// gfx950, 31B/atomic HBM write-through) are ELIMINATED via a bucket
// counting-sort by dst (256-node buckets) + LDS-only aggregation:
//   hist -> hierarchical exclusive scan -> scatter (LDS cursors) ->
//   per-bucket LDS deg/aggregate with fused node epilogues.

constexpr int N_NODES = 200000;
constexpr int N_EDGES = 12800000;
constexpr int RANGE_SHIFT = 8;                       // 256 nodes / bucket
constexpr int K_BUCKETS = (N_NODES + 255) / 256;     // 782
constexpr int SORT_BLOCKS = 1024;
constexpr int CHUNK = N_EDGES / SORT_BLOCKS;         // 12500 exactly

// ---------------- sort phase ----------------

__global__ __launch_bounds__(256) void hist_kernel(const int* __restrict__ dst,
                                                   unsigned* __restrict__ blockHist) {
    __shared__ unsigned h[K_BUCKETS];
    for (int i = threadIdx.x; i < K_BUCKETS; i += 256) h[i] = 0;
    __syncthreads();
    int base = blockIdx.x * CHUNK;
    for (int e = base + threadIdx.x; e < base + CHUNK; e += 256)
        atomicAdd(&h[((unsigned)dst[e]) >> RANGE_SHIFT], 1u);
    __syncthreads();
    unsigned* row = blockHist + (size_t)blockIdx.x * K_BUCKETS;
    for (int i = threadIdx.x; i < K_BUCKETS; i += 256) row[i] = h[i];
}

// One block per bucket: exclusive scan over the SORT_BLOCKS per-block counts.
__global__ __launch_bounds__(256) void scan_perblock_kernel(unsigned* __restrict__ blockHist,
                                                            unsigned* __restrict__ bucketTotal) {
    int b = blockIdx.x, t = threadIdx.x;
    unsigned v[4], run = 0;
#pragma unroll
    for (int j = 0; j < 4; j++) v[j] = blockHist[(size_t)(4 * t + j) * K_BUCKETS + b];
#pragma unroll
    for (int j = 0; j < 4; j++) { unsigned tmp = v[j]; v[j] = run; run += tmp; }
    __shared__ unsigned sh[256];
    sh[t] = run;
    __syncthreads();
    for (int off = 1; off < 256; off <<= 1) {
        unsigned add = (t >= off) ? sh[t - off] : 0u;
        __syncthreads();
        sh[t] += add;
        __syncthreads();
    }
    unsigned excl = sh[t] - run;   // exclusive prefix of this thread's chunk
#pragma unroll
    for (int j = 0; j < 4; j++) blockHist[(size_t)(4 * t + j) * K_BUCKETS + b] = excl + v[j];
    if (t == 255) bucketTotal[b] = sh[255];
}

// Single block: exclusive scan of bucket totals -> bucketStart[0..K].
__global__ __launch_bounds__(1024) void scan_buckets_kernel(const unsigned* __restrict__ bucketTotal,
                                                            unsigned* __restrict__ bucketStart) {
    __shared__ unsigned sh[1024];
    int t = threadIdx.x;
    unsigned v = (t < K_BUCKETS) ? bucketTotal[t] : 0u;
    sh[t] = v;
    __syncthreads();
    for (int off = 1; off < 1024; off <<= 1) {
        unsigned add = (t >= off) ? sh[t - off] : 0u;
        __syncthreads();
        sh[t] += add;
        __syncthreads();
    }
    if (t < K_BUCKETS) bucketStart[t] = sh[t] - v;
    if (t == K_BUCKETS - 1) bucketStart[K_BUCKETS] = sh[t];
}

// Scatter edges into bucket-sorted order. Packed 4B: src (18b) | local_dst (8b)<<18.
__global__ __launch_bounds__(256) void scatter_kernel(const int* __restrict__ src,
                                                      const int* __restrict__ dst,
                                                      const unsigned* __restrict__ blockHist,
                                                      const unsigned* __restrict__ bucketStart,
                                                      unsigned* __restrict__ sorted) {
    __shared__ unsigned cur[K_BUCKETS];
    const unsigned* row = blockHist + (size_t)blockIdx.x * K_BUCKETS;
    for (int i = threadIdx.x; i < K_BUCKETS; i += 256) cur[i] = bucketStart[i] + row[i];
    __syncthreads();
    int base = blockIdx.x * CHUNK;
    for (int e = base + threadIdx.x; e < base + CHUNK; e += 256) {
        unsigned d = (unsigned)dst[e];
        unsigned s = (unsigned)src[e];
        unsigned pos = atomicAdd(&cur[d >> RANGE_SHIFT], 1u);
        sorted[pos] = s | ((d & 255u) << 18);
    }
}

// ---------------- GCN phase (one block per bucket, LDS only) ----------------

__global__ __launch_bounds__(256) void deg_node1_kernel(const unsigned* __restrict__ sorted,
                                                        const unsigned* __restrict__ bucketStart,
                                                        const float2* __restrict__ x,
                                                        float* __restrict__ dinv,
                                                        float2* __restrict__ u) {
    __shared__ unsigned cnt[256];
    int t = threadIdx.x;
    cnt[t] = 0;
    __syncthreads();
    unsigned s0 = bucketStart[blockIdx.x], s1 = bucketStart[blockIdx.x + 1];
    for (unsigned e = s0 + t; e < s1; e += 256)
        atomicAdd(&cnt[(sorted[e] >> 18) & 255u], 1u);
    __syncthreads();
    int node = blockIdx.x * 256 + t;
    if (node >= N_NODES) return;
    float di = rsqrtf((float)(cnt[t] + 1u));   // +1 self loop
    dinv[node] = di;
    float2 xi = x[node];
    u[node] = make_float2(di * xi.x, di * xi.y);
}

__global__ __launch_bounds__(256) void agg1_node2_kernel(const unsigned* __restrict__ sorted,
                                                         const unsigned* __restrict__ bucketStart,
                                                         const float2* __restrict__ u,
                                                         const float* __restrict__ dinv,
                                                         const float* __restrict__ W1,
                                                         const float* __restrict__ b1,
                                                         const float* __restrict__ W2,
                                                         float2* __restrict__ g2) {
    __shared__ float ax[256], ay[256];
    int t = threadIdx.x;
    ax[t] = 0.f; ay[t] = 0.f;
    __syncthreads();
    unsigned s0 = bucketStart[blockIdx.x], s1 = bucketStart[blockIdx.x + 1];
    for (unsigned e = s0 + t; e < s1; e += 256) {
        unsigned w = sorted[e];
        float2 v = u[w & 0x3FFFFu];
        unsigned l = (w >> 18) & 255u;
        atomicAdd(&ax[l], v.x);
        atomicAdd(&ay[l], v.y);
    }
    __syncthreads();
    int node = blockIdx.x * 256 + t;
    if (node >= N_NODES) return;
    float di = dinv[node];
    float2 uu = u[node];
    float c0 = di * (ax[t] + uu.x);
    float c1 = di * (ay[t] + uu.y);
    float a0 = 0.f, a1 = 0.f;
#pragma unroll
    for (int f = 0; f < 16; f++) {
        float o = fmaxf(c0 * W1[f] + c1 * W1[16 + f] + b1[f], 0.f);  // W1 (2,16)
        a0 += o * W2[2 * f];                                         // W2 (16,2)
        a1 += o * W2[2 * f + 1];
    }
    g2[node] = make_float2(di * a0, di * a1);
}

__global__ __launch_bounds__(256) void agg2_node3_kernel(const unsigned* __restrict__ sorted,
                                                         const unsigned* __restrict__ bucketStart,
                                                         const float2* __restrict__ g2,
                                                         const float* __restrict__ dinv,
                                                         const float* __restrict__ b2,
                                                         float2* __restrict__ out) {
    __shared__ float ax[256], ay[256];
    int t = threadIdx.x;
    ax[t] = 0.f; ay[t] = 0.f;
    __syncthreads();
    unsigned s0 = bucketStart[blockIdx.x], s1 = bucketStart[blockIdx.x + 1];
    for (unsigned e = s0 + t; e < s1; e += 256) {
        unsigned w = sorted[e];
        float2 v = g2[w & 0x3FFFFu];
        unsigned l = (w >> 18) & 255u;
        atomicAdd(&ax[l], v.x);
        atomicAdd(&ay[l], v.y);
    }
    __syncthreads();
    int node = blockIdx.x * 256 + t;
    if (node >= N_NODES) return;
    float di = dinv[node];
    float2 g = g2[node];
    out[node] = make_float2(di * (ax[t] + g.x) + b2[0],
                            di * (ay[t] + g.y) + b2[1]);
}

// ---------------- fallback path (R2-style, needs only 8 MB ws) ----------------

__global__ __launch_bounds__(256) void fb_deg(const int* __restrict__ dst, int* __restrict__ degi) {
    int e = blockIdx.x * 256 + threadIdx.x;
    if (e < N_EDGES) atomicAdd(&degi[dst[e]], 1);
}
__global__ __launch_bounds__(256) void fb_node1(const float* __restrict__ x, const int* __restrict__ degi,
                                                float* __restrict__ dinv, float2* __restrict__ u) {
    int i = blockIdx.x * 256 + threadIdx.x;
    if (i >= N_NODES) return;
    float di = rsqrtf((float)(degi[i] + 1));
    dinv[i] = di;
    float2 xi = ((const float2*)x)[i];
    u[i] = make_float2(di * xi.x, di * xi.y);
}
__global__ __launch_bounds__(256) void fb_agg(const int* __restrict__ src, const int* __restrict__ dst,
                                              const float2* __restrict__ table, float* __restrict__ acc) {
    int e = blockIdx.x * 256 + threadIdx.x;
    if (e >= N_EDGES) return;
    float2 v = table[src[e]];
    size_t d = dst[e];
    unsafeAtomicAdd(&acc[2 * d], v.x);
    unsafeAtomicAdd(&acc[2 * d + 1], v.y);
}
__global__ __launch_bounds__(256) void fb_node2(const float2* __restrict__ u, const float2* __restrict__ A1,
                                                const float* __restrict__ W1, const float* __restrict__ b1,
                                                const float* __restrict__ W2, const float* __restrict__ dinv,
                                                float2* __restrict__ g2) {
    int i = blockIdx.x * 256 + threadIdx.x;
    if (i >= N_NODES) return;
    float di = dinv[i];
    float2 a = A1[i], uu = u[i];
    float c0 = di * (a.x + uu.x), c1 = di * (a.y + uu.y);
    float a0 = 0.f, a1 = 0.f;
#pragma unroll
    for (int f = 0; f < 16; f++) {
        float o = fmaxf(c0 * W1[f] + c1 * W1[16 + f] + b1[f], 0.f);
        a0 += o * W2[2 * f];
        a1 += o * W2[2 * f + 1];
    }
    g2[i] = make_float2(di * a0, di * a1);
}
__global__ __launch_bounds__(256) void fb_node3(const float2* __restrict__ g2, const float2* __restrict__ A2,
                                                const float* __restrict__ b2, const float* __restrict__ dinv,
                                                float2* __restrict__ out) {
    int i = blockIdx.x * 256 + threadIdx.x;
    if (i >= N_NODES) return;
    float di = dinv[i];
    float2 a = A2[i], g = g2[i];
    out[i] = make_float2(di * (a.x + g.x) + b2[0], di * (a.y + g.y) + b2[1]);
}

// ---------------- launcher ----------------

extern "C" void kernel_launch(void* const* d_in, const int* in_sizes, int n_in,
                              void* d_out, int out_size, void* d_ws, size_t ws_size,
                              hipStream_t stream) {
    const float* x  = (const float*)d_in[0];
    const float* W1 = (const float*)d_in[1];
    const float* b1 = (const float*)d_in[2];
    const float* W2 = (const float*)d_in[3];
    const float* b2 = (const float*)d_in[4];
    const int* ei   = (const int*)d_in[5];   // (2,E): row 0 = src, row 1 = dst
    const int* src = ei;
    const int* dst = ei + N_EDGES;
    float2* out = (float2*)d_out;

    // Primary ws layout (4B words):
    //   sorted      [E]                      12,800,000
    //   blockHist   [SORT_BLOCKS*K]             800,768
    //   bucketTotal [K]                             782
    //   bucketStart [K+1] (+1 pad)                  784
    //   dinv        [N]                         200,000
    //   u           [2N] (8B aligned)           400,000
    //   g2          [2N]                        400,000   total ~58.4 MB
    const size_t need = (size_t)(12800000 + 800768 + 782 + 784 + 200000 + 400000 + 400000) * 4;

    if (ws_size >= need) {
        unsigned* sorted      = (unsigned*)d_ws;
        unsigned* blockHist   = sorted + N_EDGES;
        unsigned* bucketTotal = blockHist + (size_t)SORT_BLOCKS * K_BUCKETS;
        unsigned* bucketStart = bucketTotal + 782;
        float*    dinv        = (float*)(bucketStart + 784);
        float2*   u           = (float2*)(dinv + N_NODES);
        float2*   g2          = u + N_NODES;

        hist_kernel<<<SORT_BLOCKS, 256, 0, stream>>>(dst, blockHist);
        scan_perblock_kernel<<<K_BUCKETS, 256, 0, stream>>>(blockHist, bucketTotal);
        scan_buckets_kernel<<<1, 1024, 0, stream>>>(bucketTotal, bucketStart);
        scatter_kernel<<<SORT_BLOCKS, 256, 0, stream>>>(src, dst, blockHist, bucketStart, sorted);
        deg_node1_kernel<<<K_BUCKETS, 256, 0, stream>>>(sorted, bucketStart, (const float2*)x, dinv, u);
        agg1_node2_kernel<<<K_BUCKETS, 256, 0, stream>>>(sorted, bucketStart, u, dinv, W1, b1, W2, g2);
        agg2_node3_kernel<<<K_BUCKETS, 256, 0, stream>>>(sorted, bucketStart, g2, dinv, b2, out);
    } else {
        // R2-style fallback (8 MB ws): global atomics, ~3.1 ms.
        float* ws = (float*)d_ws;
        int*   degi = (int*)ws;
        float* A1   = ws + N_NODES;
        float* A2   = A1 + 2 * (size_t)N_NODES;
        float* dinv = A2 + 2 * (size_t)N_NODES;
        float2* u   = (float2*)(dinv + N_NODES);
        float2* g2  = u + N_NODES;
        constexpr int EB = (N_EDGES + 255) / 256;
        constexpr int NB = (N_NODES + 255) / 256;
        hipMemsetAsync(degi, 0, 5 * (size_t)N_NODES * sizeof(float), stream);
        fb_deg<<<EB, 256, 0, stream>>>(dst, degi);
        fb_node1<<<NB, 256, 0, stream>>>(x, degi, dinv, u);
        fb_agg<<<EB, 256, 0, stream>>>(src, dst, u, A1);
        fb_node2<<<NB, 256, 0, stream>>>(u, (const float2*)A1, W1, b1, W2, dinv, g2);
        fb_agg<<<EB, 256, 0, stream>>>(src, dst, g2, A2);
        fb_node3<<<NB, 256, 0, stream>>>(g2, (const float2*)A2, b2, dinv, out);
    }
}

// Round 5
// 650.990 us; speedup vs baseline: 6.9486x; 1.2144x over previous
//
#include <hip/hip_runtime.h>

// GCN 2-layer: N=200000, E=12800000, features 2 -> 16 -> 2.
// R2: rank trick -- aggregate only 2-dim vectors (before W1 / after W2).
// R4: bucket counting-sort by dst (256-node buckets) + LDS-only aggregation;
//     global atomics eliminated (measured ~20G line-transactions/s ceiling).
// R5: scatter rewritten as block-local LDS counting sort + in-order copy-out.
//     R4's scatter wrote 4B at per-bucket GLOBAL cursors -> every output line
//     shared by many blocks/XCDs -> 341 MB HBM writes for 51.2 MB of data.
//     Now each block sorts its chunk in LDS and streams each per-(block,
//     bucket) run to its contiguous global range: coalesced wave stores,
//     line sharing only at run boundaries.

constexpr int N_NODES = 200000;
constexpr int N_EDGES = 12800000;
constexpr int RANGE_SHIFT = 8;                       // 256 nodes / bucket
constexpr int K_BUCKETS = (N_NODES + 255) / 256;     // 782
constexpr int SORT_BLOCKS = 2048;
constexpr int CHUNK = N_EDGES / SORT_BLOCKS;         // 6250 exactly
constexpr int SCAN_R = SORT_BLOCKS / 256;            // 8

// ---------------- sort phase ----------------

__global__ __launch_bounds__(256) void hist_kernel(const int* __restrict__ dst,
                                                   unsigned* __restrict__ blockHist) {
    __shared__ unsigned h[K_BUCKETS];
    for (int i = threadIdx.x; i < K_BUCKETS; i += 256) h[i] = 0;
    __syncthreads();
    int base = blockIdx.x * CHUNK;
    for (int e = base + threadIdx.x; e < base + CHUNK; e += 256)
        atomicAdd(&h[((unsigned)dst[e]) >> RANGE_SHIFT], 1u);
    __syncthreads();
    unsigned* row = blockHist + (size_t)blockIdx.x * K_BUCKETS;
    for (int i = threadIdx.x; i < K_BUCKETS; i += 256) row[i] = h[i];
}

// One block per bucket: exclusive scan over the SORT_BLOCKS per-block counts.
__global__ __launch_bounds__(256) void scan_perblock_kernel(unsigned* __restrict__ blockHist,
                                                            unsigned* __restrict__ bucketTotal) {
    int b = blockIdx.x, t = threadIdx.x;
    unsigned v[SCAN_R], run = 0;
#pragma unroll
    for (int j = 0; j < SCAN_R; j++) v[j] = blockHist[(size_t)(SCAN_R * t + j) * K_BUCKETS + b];
#pragma unroll
    for (int j = 0; j < SCAN_R; j++) { unsigned tmp = v[j]; v[j] = run; run += tmp; }
    __shared__ unsigned sh[256];
    sh[t] = run;
    __syncthreads();
    for (int off = 1; off < 256; off <<= 1) {
        unsigned add = (t >= off) ? sh[t - off] : 0u;
        __syncthreads();
        sh[t] += add;
        __syncthreads();
    }
    unsigned excl = sh[t] - run;   // exclusive prefix of this thread's run
#pragma unroll
    for (int j = 0; j < SCAN_R; j++)
        blockHist[(size_t)(SCAN_R * t + j) * K_BUCKETS + b] = excl + v[j];
    if (t == 255) bucketTotal[b] = sh[255];
}

// Single block: exclusive scan of bucket totals -> bucketStart[0..K].
__global__ __launch_bounds__(1024) void scan_buckets_kernel(const unsigned* __restrict__ bucketTotal,
                                                            unsigned* __restrict__ bucketStart) {
    __shared__ unsigned sh[1024];
    int t = threadIdx.x;
    unsigned v = (t < K_BUCKETS) ? bucketTotal[t] : 0u;
    sh[t] = v;
    __syncthreads();
    for (int off = 1; off < 1024; off <<= 1) {
        unsigned add = (t >= off) ? sh[t - off] : 0u;
        __syncthreads();
        sh[t] += add;
        __syncthreads();
    }
    if (t < K_BUCKETS) bucketStart[t] = sh[t] - v;
    if (t == K_BUCKETS - 1) bucketStart[K_BUCKETS] = sh[t];
}

// Block-local counting sort in LDS, then in-order coalesced copy-out.
// Packed 4B entry: src (18b) | local_dst (8b) << 18.
__global__ __launch_bounds__(256) void scatter_kernel(const int* __restrict__ src,
                                                      const int* __restrict__ dst,
                                                      const unsigned* __restrict__ blockHist,
                                                      const unsigned* __restrict__ bucketStart,
                                                      unsigned* __restrict__ sorted) {
    __shared__ unsigned s_hist[K_BUCKETS];
    __shared__ unsigned s_cur[K_BUCKETS];
    __shared__ int      s_base[K_BUCKETS];
    __shared__ unsigned ssum[256];
    __shared__ unsigned ent[CHUNK];
    __shared__ unsigned short bk[CHUNK];

    int t = threadIdx.x;
    int base = blockIdx.x * CHUNK;
    for (int i = t; i < K_BUCKETS; i += 256) s_hist[i] = 0;
    __syncthreads();

    // (1) local histogram
    for (int e = base + t; e < base + CHUNK; e += 256)
        atomicAdd(&s_hist[((unsigned)dst[e]) >> RANGE_SHIFT], 1u);
    __syncthreads();

    // (2) local exclusive scan (782 counters, 4 per thread)
    unsigned v[4], run = 0;
#pragma unroll
    for (int j = 0; j < 4; j++) {
        int idx = 4 * t + j;
        v[j] = (idx < K_BUCKETS) ? s_hist[idx] : 0u;
    }
#pragma unroll
    for (int j = 0; j < 4; j++) { unsigned tmp = v[j]; v[j] = run; run += tmp; }
    ssum[t] = run;
    __syncthreads();
    for (int off = 1; off < 256; off <<= 1) {
        unsigned add = (t >= off) ? ssum[t - off] : 0u;
        __syncthreads();
        ssum[t] += add;
        __syncthreads();
    }
    unsigned excl = ssum[t] - run;
    const unsigned* row = blockHist + (size_t)blockIdx.x * K_BUCKETS;
#pragma unroll
    for (int j = 0; j < 4; j++) {
        int idx = 4 * t + j;
        if (idx < K_BUCKETS) {
            unsigned st = excl + v[j];             // local start
            s_cur[idx] = st;
            s_base[idx] = (int)(bucketStart[idx] + row[idx]) - (int)st;
        }
    }
    __syncthreads();

    // (3) local scatter into LDS (sorted by bucket within block)
    for (int e = base + t; e < base + CHUNK; e += 256) {
        unsigned d = (unsigned)dst[e];
        unsigned s = (unsigned)src[e];
        unsigned b = d >> RANGE_SHIFT;
        unsigned lpos = atomicAdd(&s_cur[b], 1u);
        ent[lpos] = s | ((d & 255u) << 18);
        bk[lpos] = (unsigned short)b;
    }
    __syncthreads();

    // (4) in-order copy-out: per-(block,bucket) runs are contiguous globally
    for (int i = t; i < CHUNK; i += 256) {
        unsigned b = bk[i];
        sorted[s_base[b] + i] = ent[i];
    }
}

// ---------------- GCN phase (one block per bucket, LDS only) ----------------

__global__ __launch_bounds__(256) void deg_node1_kernel(const unsigned* __restrict__ sorted,
                                                        const unsigned* __restrict__ bucketStart,
                                                        const float2* __restrict__ x,
                                                        float* __restrict__ dinv,
                                                        float2* __restrict__ u) {
    __shared__ unsigned cnt[256];
    int t = threadIdx.x;
    cnt[t] = 0;
    __syncthreads();
    unsigned s0 = bucketStart[blockIdx.x], s1 = bucketStart[blockIdx.x + 1];
    for (unsigned e = s0 + t; e < s1; e += 256)
        atomicAdd(&cnt[(sorted[e] >> 18) & 255u], 1u);
    __syncthreads();
    int node = blockIdx.x * 256 + t;
    if (node >= N_NODES) return;
    float di = rsqrtf((float)(cnt[t] + 1u));   // +1 self loop
    dinv[node] = di;
    float2 xi = x[node];
    u[node] = make_float2(di * xi.x, di * xi.y);
}

__global__ __launch_bounds__(256) void agg1_node2_kernel(const unsigned* __restrict__ sorted,
                                                         const unsigned* __restrict__ bucketStart,
                                                         const float2* __restrict__ u,
                                                         const float* __restrict__ dinv,
                                                         const float* __restrict__ W1,
                                                         const float* __restrict__ b1,
                                                         const float* __restrict__ W2,
                                                         float2* __restrict__ g2) {
    __shared__ float ax[256], ay[256];
    int t = threadIdx.x;
    ax[t] = 0.f; ay[t] = 0.f;
    __syncthreads();
    unsigned s0 = bucketStart[blockIdx.x], s1 = bucketStart[blockIdx.x + 1];
    for (unsigned e = s0 + t; e < s1; e += 256) {
        unsigned w = sorted[e];
        float2 v = u[w & 0x3FFFFu];
        unsigned l = (w >> 18) & 255u;
        atomicAdd(&ax[l], v.x);
        atomicAdd(&ay[l], v.y);
    }
    __syncthreads();
    int node = blockIdx.x * 256 + t;
    if (node >= N_NODES) return;
    float di = dinv[node];
    float2 uu = u[node];
    float c0 = di * (ax[t] + uu.x);
    float c1 = di * (ay[t] + uu.y);
    float a0 = 0.f, a1 = 0.f;
#pragma unroll
    for (int f = 0; f < 16; f++) {
        float o = fmaxf(c0 * W1[f] + c1 * W1[16 + f] + b1[f], 0.f);  // W1 (2,16)
        a0 += o * W2[2 * f];                                         // W2 (16,2)
        a1 += o * W2[2 * f + 1];
    }
    g2[node] = make_float2(di * a0, di * a1);
}

__global__ __launch_bounds__(256) void agg2_node3_kernel(const unsigned* __restrict__ sorted,
                                                         const unsigned* __restrict__ bucketStart,
                                                         const float2* __restrict__ g2,
                                                         const float* __restrict__ dinv,
                                                         const float* __restrict__ b2,
                                                         float2* __restrict__ out) {
    __shared__ float ax[256], ay[256];
    int t = threadIdx.x;
    ax[t] = 0.f; ay[t] = 0.f;
    __syncthreads();
    unsigned s0 = bucketStart[blockIdx.x], s1 = bucketStart[blockIdx.x + 1];
    for (unsigned e = s0 + t; e < s1; e += 256) {
        unsigned w = sorted[e];
        float2 v = g2[w & 0x3FFFFu];
        unsigned l = (w >> 18) & 255u;
        atomicAdd(&ax[l], v.x);
        atomicAdd(&ay[l], v.y);
    }
    __syncthreads();
    int node = blockIdx.x * 256 + t;
    if (node >= N_NODES) return;
    float di = dinv[node];
    float2 g = g2[node];
    out[node] = make_float2(di * (ax[t] + g.x) + b2[0],
                            di * (ay[t] + g.y) + b2[1]);
}

// ---------------- fallback path (R2-style, needs only 8 MB ws) ----------------

__global__ __launch_bounds__(256) void fb_deg(const int* __restrict__ dst, int* __restrict__ degi) {
    int e = blockIdx.x * 256 + threadIdx.x;
    if (e < N_EDGES) atomicAdd(&degi[dst[e]], 1);
}
__global__ __launch_bounds__(256) void fb_node1(const float* __restrict__ x, const int* __restrict__ degi,
                                                float* __restrict__ dinv, float2* __restrict__ u) {
    int i = blockIdx.x * 256 + threadIdx.x;
    if (i >= N_NODES) return;
    float di = rsqrtf((float)(degi[i] + 1));
    dinv[i] = di;
    float2 xi = ((const float2*)x)[i];
    u[i] = make_float2(di * xi.x, di * xi.y);
}
__global__ __launch_bounds__(256) void fb_agg(const int* __restrict__ src, const int* __restrict__ dst,
                                              const float2* __restrict__ table, float* __restrict__ acc) {
    int e = blockIdx.x * 256 + threadIdx.x;
    if (e >= N_EDGES) return;
    float2 v = table[src[e]];
    size_t d = dst[e];
    unsafeAtomicAdd(&acc[2 * d], v.x);
    unsafeAtomicAdd(&acc[2 * d + 1], v.y);
}
__global__ __launch_bounds__(256) void fb_node2(const float2* __restrict__ u, const float2* __restrict__ A1,
                                                const float* __restrict__ W1, const float* __restrict__ b1,
                                                const float* __restrict__ W2, const float* __restrict__ dinv,
                                                float2* __restrict__ g2) {
    int i = blockIdx.x * 256 + threadIdx.x;
    if (i >= N_NODES) return;
    float di = dinv[i];
    float2 a = A1[i], uu = u[i];
    float c0 = di * (a.x + uu.x), c1 = di * (a.y + uu.y);
    float a0 = 0.f, a1 = 0.f;
#pragma unroll
    for (int f = 0; f < 16; f++) {
        float o = fmaxf(c0 * W1[f] + c1 * W1[16 + f] + b1[f], 0.f);
        a0 += o * W2[2 * f];
        a1 += o * W2[2 * f + 1];
    }
    g2[i] = make_float2(di * a0, di * a1);
}
__global__ __launch_bounds__(256) void fb_node3(const float2* __restrict__ g2, const float2* __restrict__ A2,
                                                const float* __restrict__ b2, const float* __restrict__ dinv,
                                                float2* __restrict__ out) {
    int i = blockIdx.x * 256 + threadIdx.x;
    if (i >= N_NODES) return;
    float di = dinv[i];
    float2 a = A2[i], g = g2[i];
    out[i] = make_float2(di * (a.x + g.x) + b2[0], di * (a.y + g.y) + b2[1]);
}

// ---------------- launcher ----------------

extern "C" void kernel_launch(void* const* d_in, const int* in_sizes, int n_in,
                              void* d_out, int out_size, void* d_ws, size_t ws_size,
                              hipStream_t stream) {
    const float* x  = (const float*)d_in[0];
    const float* W1 = (const float*)d_in[1];
    const float* b1 = (const float*)d_in[2];
    const float* W2 = (const float*)d_in[3];
    const float* b2 = (const float*)d_in[4];
    const int* ei   = (const int*)d_in[5];   // (2,E): row 0 = src, row 1 = dst
    const int* src = ei;
    const int* dst = ei + N_EDGES;
    float2* out = (float2*)d_out;

    // Primary ws layout (4B words):
    //   sorted      [E]                      12,800,000
    //   blockHist   [SORT_BLOCKS*K]           1,601,536
    //   bucketTotal [K]                             782
    //   bucketStart [K+1] (+1 pad)                  784
    //   dinv        [N]                         200,000
    //   u           [2N] (8B aligned)           400,000
    //   g2          [2N]                        400,000   total ~61.6 MB
    const size_t need = ((size_t)N_EDGES + (size_t)SORT_BLOCKS * K_BUCKETS + 782 + 784
                         + N_NODES + 2 * (size_t)N_NODES + 2 * (size_t)N_NODES) * 4;

    if (ws_size >= need) {
        unsigned* sorted      = (unsigned*)d_ws;
        unsigned* blockHist   = sorted + N_EDGES;
        unsigned* bucketTotal = blockHist + (size_t)SORT_BLOCKS * K_BUCKETS;
        unsigned* bucketStart = bucketTotal + 782;
        float*    dinv        = (float*)(bucketStart + 784);
        float2*   u           = (float2*)(dinv + N_NODES);
        float2*   g2          = u + N_NODES;

        hist_kernel<<<SORT_BLOCKS, 256, 0, stream>>>(dst, blockHist);
        scan_perblock_kernel<<<K_BUCKETS, 256, 0, stream>>>(blockHist, bucketTotal);
        scan_buckets_kernel<<<1, 1024, 0, stream>>>(bucketTotal, bucketStart);
        scatter_kernel<<<SORT_BLOCKS, 256, 0, stream>>>(src, dst, blockHist, bucketStart, sorted);
        deg_node1_kernel<<<K_BUCKETS, 256, 0, stream>>>(sorted, bucketStart, (const float2*)x, dinv, u);
        agg1_node2_kernel<<<K_BUCKETS, 256, 0, stream>>>(sorted, bucketStart, u, dinv, W1, b1, W2, g2);
        agg2_node3_kernel<<<K_BUCKETS, 256, 0, stream>>>(sorted, bucketStart, g2, dinv, b2, out);
    } else {
        // R2-style fallback (8 MB ws): global atomics, ~3.1 ms.
        float* ws = (float*)d_ws;
        int*   degi = (int*)ws;
        float* A1   = ws + N_NODES;
        float* A2   = A1 + 2 * (size_t)N_NODES;
        float* dinv = A2 + 2 * (size_t)N_NODES;
        float2* u   = (float2*)(dinv + N_NODES);
        float2* g2  = u + N_NODES;
        constexpr int EB = (N_EDGES + 255) / 256;
        constexpr int NB = (N_NODES + 255) / 256;
        hipMemsetAsync(degi, 0, 5 * (size_t)N_NODES * sizeof(float), stream);
        fb_deg<<<EB, 256, 0, stream>>>(dst, degi);
        fb_node1<<<NB, 256, 0, stream>>>(x, degi, dinv, u);
        fb_agg<<<EB, 256, 0, stream>>>(src, dst, u, A1);
        fb_node2<<<NB, 256, 0, stream>>>(u, (const float2*)A1, W1, b1, W2, dinv, g2);
        fb_agg<<<EB, 256, 0, stream>>>(src, dst, g2, A2);
        fb_node3<<<NB, 256, 0, stream>>>(g2, (const float2*)A2, b2, dinv, out);
    }
}

// Round 6
// 583.687 us; speedup vs baseline: 7.7498x; 1.1153x over previous
//
#include <hip/hip_runtime.h>

// GCN 2-layer: N=200000, E=12800000, features 2 -> 16 -> 2.
// R2: rank trick -- aggregate only 2-dim vectors (before W1 / after W2).
// R4: bucket counting-sort by dst (256-node buckets) + LDS-only aggregation.
// R5: scatter = block-local LDS counting sort + in-order coalesced copy-out.
// R6: agg/deg latency fix. R5's agg kernels ran 177 us at HBM 2.4% / VALU
//     1.3% / occ 26% -- gather-latency-bound (782 blocks, 1 gather in
//     flight). Now each bucket's edges are split across 4 blocks (3128-block
//     grids) with 4-way unrolled gather streams; partial sums (2KB/block) go
//     into the dead blockHist region and node kernels merge 4 partials.

constexpr int N_NODES = 200000;
constexpr int N_EDGES = 12800000;
constexpr int RANGE_SHIFT = 8;                       // 256 nodes / bucket
constexpr int K_BUCKETS = (N_NODES + 255) / 256;     // 782
constexpr int SORT_BLOCKS = 2048;
constexpr int CHUNK = N_EDGES / SORT_BLOCKS;         // 6250 exactly
constexpr int SCAN_R = SORT_BLOCKS / 256;            // 8
constexpr int SEG = 4;                               // segments per bucket

// ---------------- sort phase ----------------

__global__ __launch_bounds__(256) void hist_kernel(const int* __restrict__ dst,
                                                   unsigned* __restrict__ blockHist) {
    __shared__ unsigned h[K_BUCKETS];
    for (int i = threadIdx.x; i < K_BUCKETS; i += 256) h[i] = 0;
    __syncthreads();
    int base = blockIdx.x * CHUNK;
    for (int e = base + threadIdx.x; e < base + CHUNK; e += 256)
        atomicAdd(&h[((unsigned)dst[e]) >> RANGE_SHIFT], 1u);
    __syncthreads();
    unsigned* row = blockHist + (size_t)blockIdx.x * K_BUCKETS;
    for (int i = threadIdx.x; i < K_BUCKETS; i += 256) row[i] = h[i];
}

// One block per bucket: exclusive scan over the SORT_BLOCKS per-block counts.
__global__ __launch_bounds__(256) void scan_perblock_kernel(unsigned* __restrict__ blockHist,
                                                            unsigned* __restrict__ bucketTotal) {
    int b = blockIdx.x, t = threadIdx.x;
    unsigned v[SCAN_R], run = 0;
#pragma unroll
    for (int j = 0; j < SCAN_R; j++) v[j] = blockHist[(size_t)(SCAN_R * t + j) * K_BUCKETS + b];
#pragma unroll
    for (int j = 0; j < SCAN_R; j++) { unsigned tmp = v[j]; v[j] = run; run += tmp; }
    __shared__ unsigned sh[256];
    sh[t] = run;
    __syncthreads();
    for (int off = 1; off < 256; off <<= 1) {
        unsigned add = (t >= off) ? sh[t - off] : 0u;
        __syncthreads();
        sh[t] += add;
        __syncthreads();
    }
    unsigned excl = sh[t] - run;
#pragma unroll
    for (int j = 0; j < SCAN_R; j++)
        blockHist[(size_t)(SCAN_R * t + j) * K_BUCKETS + b] = excl + v[j];
    if (t == 255) bucketTotal[b] = sh[255];
}

// Single block: exclusive scan of bucket totals -> bucketStart[0..K].
__global__ __launch_bounds__(1024) void scan_buckets_kernel(const unsigned* __restrict__ bucketTotal,
                                                            unsigned* __restrict__ bucketStart) {
    __shared__ unsigned sh[1024];
    int t = threadIdx.x;
    unsigned v = (t < K_BUCKETS) ? bucketTotal[t] : 0u;
    sh[t] = v;
    __syncthreads();
    for (int off = 1; off < 1024; off <<= 1) {
        unsigned add = (t >= off) ? sh[t - off] : 0u;
        __syncthreads();
        sh[t] += add;
        __syncthreads();
    }
    if (t < K_BUCKETS) bucketStart[t] = sh[t] - v;
    if (t == K_BUCKETS - 1) bucketStart[K_BUCKETS] = sh[t];
}

// Block-local counting sort in LDS, then in-order coalesced copy-out.
// Packed 4B entry: src (18b) | local_dst (8b) << 18.
__global__ __launch_bounds__(256) void scatter_kernel(const int* __restrict__ src,
                                                      const int* __restrict__ dst,
                                                      const unsigned* __restrict__ blockHist,
                                                      const unsigned* __restrict__ bucketStart,
                                                      unsigned* __restrict__ sorted) {
    __shared__ unsigned s_hist[K_BUCKETS];
    __shared__ unsigned s_cur[K_BUCKETS];
    __shared__ int      s_base[K_BUCKETS];
    __shared__ unsigned ssum[256];
    __shared__ unsigned ent[CHUNK];
    __shared__ unsigned short bk[CHUNK];

    int t = threadIdx.x;
    int base = blockIdx.x * CHUNK;
    for (int i = t; i < K_BUCKETS; i += 256) s_hist[i] = 0;
    __syncthreads();

    for (int e = base + t; e < base + CHUNK; e += 256)
        atomicAdd(&s_hist[((unsigned)dst[e]) >> RANGE_SHIFT], 1u);
    __syncthreads();

    unsigned v[4], run = 0;
#pragma unroll
    for (int j = 0; j < 4; j++) {
        int idx = 4 * t + j;
        v[j] = (idx < K_BUCKETS) ? s_hist[idx] : 0u;
    }
#pragma unroll
    for (int j = 0; j < 4; j++) { unsigned tmp = v[j]; v[j] = run; run += tmp; }
    ssum[t] = run;
    __syncthreads();
    for (int off = 1; off < 256; off <<= 1) {
        unsigned add = (t >= off) ? ssum[t - off] : 0u;
        __syncthreads();
        ssum[t] += add;
        __syncthreads();
    }
    unsigned excl = ssum[t] - run;
    const unsigned* row = blockHist + (size_t)blockIdx.x * K_BUCKETS;
#pragma unroll
    for (int j = 0; j < 4; j++) {
        int idx = 4 * t + j;
        if (idx < K_BUCKETS) {
            unsigned st = excl + v[j];
            s_cur[idx] = st;
            s_base[idx] = (int)(bucketStart[idx] + row[idx]) - (int)st;
        }
    }
    __syncthreads();

    for (int e = base + t; e < base + CHUNK; e += 256) {
        unsigned d = (unsigned)dst[e];
        unsigned s = (unsigned)src[e];
        unsigned b = d >> RANGE_SHIFT;
        unsigned lpos = atomicAdd(&s_cur[b], 1u);
        ent[lpos] = s | ((d & 255u) << 18);
        bk[lpos] = (unsigned short)b;
    }
    __syncthreads();

    for (int i = t; i < CHUNK; i += 256) {
        unsigned b = bk[i];
        sorted[s_base[b] + i] = ent[i];
    }
}

// ---------------- GCN phase ----------------
// Grids of K_BUCKETS*SEG blocks: b = blockIdx.x>>2, s = blockIdx.x&3.

__global__ __launch_bounds__(256) void deg_part_kernel(const unsigned* __restrict__ sorted,
                                                       const unsigned* __restrict__ bucketStart,
                                                       unsigned* __restrict__ pcnt) {
    __shared__ unsigned cnt[256];
    int t = threadIdx.x;
    cnt[t] = 0;
    __syncthreads();
    int b = blockIdx.x >> 2, s = blockIdx.x & 3;
    int s0 = bucketStart[b], len = bucketStart[b + 1] - s0;
    int e0 = s0 + (len * s) / SEG;
    int e1 = s0 + (len * (s + 1)) / SEG;
    int e = e0 + t;
    for (; e < e1 - 768; e += 1024) {
        unsigned w0 = sorted[e], w1 = sorted[e + 256], w2 = sorted[e + 512], w3 = sorted[e + 768];
        atomicAdd(&cnt[(w0 >> 18) & 255u], 1u);
        atomicAdd(&cnt[(w1 >> 18) & 255u], 1u);
        atomicAdd(&cnt[(w2 >> 18) & 255u], 1u);
        atomicAdd(&cnt[(w3 >> 18) & 255u], 1u);
    }
    for (; e < e1; e += 256)
        atomicAdd(&cnt[(sorted[e] >> 18) & 255u], 1u);
    __syncthreads();
    pcnt[(size_t)blockIdx.x * 256 + t] = cnt[t];
}

__global__ __launch_bounds__(256) void node1_kernel(const float2* __restrict__ x,
                                                    const unsigned* __restrict__ pcnt,
                                                    float* __restrict__ dinv,
                                                    float2* __restrict__ u) {
    int i = blockIdx.x * 256 + threadIdx.x;
    if (i >= N_NODES) return;
    int b = i >> 8, l = i & 255;
    unsigned c = 1;  // +1 self loop
#pragma unroll
    for (int s = 0; s < SEG; s++) c += pcnt[(size_t)(b * SEG + s) * 256 + l];
    float di = rsqrtf((float)c);
    dinv[i] = di;
    float2 xi = x[i];
    u[i] = make_float2(di * xi.x, di * xi.y);
}

// Partial aggregation: gather table[src] for one bucket-segment, LDS-sum,
// write a float2[256] partial.
__global__ __launch_bounds__(256) void agg_part_kernel(const unsigned* __restrict__ sorted,
                                                       const unsigned* __restrict__ bucketStart,
                                                       const float2* __restrict__ table,
                                                       float2* __restrict__ part) {
    __shared__ float ax[256], ay[256];
    int t = threadIdx.x;
    ax[t] = 0.f; ay[t] = 0.f;
    __syncthreads();
    int b = blockIdx.x >> 2, s = blockIdx.x & 3;
    int s0 = bucketStart[b], len = bucketStart[b + 1] - s0;
    int e0 = s0 + (len * s) / SEG;
    int e1 = s0 + (len * (s + 1)) / SEG;
    int e = e0 + t;
    for (; e < e1 - 768; e += 1024) {
        unsigned w0 = sorted[e], w1 = sorted[e + 256], w2 = sorted[e + 512], w3 = sorted[e + 768];
        float2 v0 = table[w0 & 0x3FFFFu];
        float2 v1 = table[w1 & 0x3FFFFu];
        float2 v2 = table[w2 & 0x3FFFFu];
        float2 v3 = table[w3 & 0x3FFFFu];
        atomicAdd(&ax[(w0 >> 18) & 255u], v0.x); atomicAdd(&ay[(w0 >> 18) & 255u], v0.y);
        atomicAdd(&ax[(w1 >> 18) & 255u], v1.x); atomicAdd(&ay[(w1 >> 18) & 255u], v1.y);
        atomicAdd(&ax[(w2 >> 18) & 255u], v2.x); atomicAdd(&ay[(w2 >> 18) & 255u], v2.y);
        atomicAdd(&ax[(w3 >> 18) & 255u], v3.x); atomicAdd(&ay[(w3 >> 18) & 255u], v3.y);
    }
    for (; e < e1; e += 256) {
        unsigned w = sorted[e];
        float2 v = table[w & 0x3FFFFu];
        unsigned l = (w >> 18) & 255u;
        atomicAdd(&ax[l], v.x);
        atomicAdd(&ay[l], v.y);
    }
    __syncthreads();
    part[(size_t)blockIdx.x * 256 + t] = make_float2(ax[t], ay[t]);
}

__global__ __launch_bounds__(256) void node2_kernel(const float2* __restrict__ u,
                                                    const float2* __restrict__ part,
                                                    const float* __restrict__ W1,
                                                    const float* __restrict__ b1,
                                                    const float* __restrict__ W2,
                                                    const float* __restrict__ dinv,
                                                    float2* __restrict__ g2) {
    int i = blockIdx.x * 256 + threadIdx.x;
    if (i >= N_NODES) return;
    int b = i >> 8, l = i & 255;
    float ax = 0.f, ay = 0.f;
#pragma unroll
    for (int s = 0; s < SEG; s++) {
        float2 p = part[(size_t)(b * SEG + s) * 256 + l];
        ax += p.x; ay += p.y;
    }
    float di = dinv[i];
    float2 uu = u[i];
    float c0 = di * (ax + uu.x);
    float c1 = di * (ay + uu.y);
    float a0 = 0.f, a1 = 0.f;
#pragma unroll
    for (int f = 0; f < 16; f++) {
        float o = fmaxf(c0 * W1[f] + c1 * W1[16 + f] + b1[f], 0.f);  // W1 (2,16)
        a0 += o * W2[2 * f];                                         // W2 (16,2)
        a1 += o * W2[2 * f + 1];
    }
    g2[i] = make_float2(di * a0, di * a1);
}

__global__ __launch_bounds__(256) void node3_kernel(const float2* __restrict__ g2,
                                                    const float2* __restrict__ part,
                                                    const float* __restrict__ b2,
                                                    const float* __restrict__ dinv,
                                                    float2* __restrict__ out) {
    int i = blockIdx.x * 256 + threadIdx.x;
    if (i >= N_NODES) return;
    int b = i >> 8, l = i & 255;
    float ax = 0.f, ay = 0.f;
#pragma unroll
    for (int s = 0; s < SEG; s++) {
        float2 p = part[(size_t)(b * SEG + s) * 256 + l];
        ax += p.x; ay += p.y;
    }
    float di = dinv[i];
    float2 g = g2[i];
    out[i] = make_float2(di * (ax + g.x) + b2[0],
                         di * (ay + g.y) + b2[1]);
}

// ---------------- fallback path (R2-style, needs only 8 MB ws) ----------------

__global__ __launch_bounds__(256) void fb_deg(const int* __restrict__ dst, int* __restrict__ degi) {
    int e = blockIdx.x * 256 + threadIdx.x;
    if (e < N_EDGES) atomicAdd(&degi[dst[e]], 1);
}
__global__ __launch_bounds__(256) void fb_node1(const float* __restrict__ x, const int* __restrict__ degi,
                                                float* __restrict__ dinv, float2* __restrict__ u) {
    int i = blockIdx.x * 256 + threadIdx.x;
    if (i >= N_NODES) return;
    float di = rsqrtf((float)(degi[i] + 1));
    dinv[i] = di;
    float2 xi = ((const float2*)x)[i];
    u[i] = make_float2(di * xi.x, di * xi.y);
}
__global__ __launch_bounds__(256) void fb_agg(const int* __restrict__ src, const int* __restrict__ dst,
                                              const float2* __restrict__ table, float* __restrict__ acc) {
    int e = blockIdx.x * 256 + threadIdx.x;
    if (e >= N_EDGES) return;
    float2 v = table[src[e]];
    size_t d = dst[e];
    unsafeAtomicAdd(&acc[2 * d], v.x);
    unsafeAtomicAdd(&acc[2 * d + 1], v.y);
}
__global__ __launch_bounds__(256) void fb_node2(const float2* __restrict__ u, const float2* __restrict__ A1,
                                                const float* __restrict__ W1, const float* __restrict__ b1,
                                                const float* __restrict__ W2, const float* __restrict__ dinv,
                                                float2* __restrict__ g2) {
    int i = blockIdx.x * 256 + threadIdx.x;
    if (i >= N_NODES) return;
    float di = dinv[i];
    float2 a = A1[i], uu = u[i];
    float c0 = di * (a.x + uu.x), c1 = di * (a.y + uu.y);
    float a0 = 0.f, a1 = 0.f;
#pragma unroll
    for (int f = 0; f < 16; f++) {
        float o = fmaxf(c0 * W1[f] + c1 * W1[16 + f] + b1[f], 0.f);
        a0 += o * W2[2 * f];
        a1 += o * W2[2 * f + 1];
    }
    g2[i] = make_float2(di * a0, di * a1);
}
__global__ __launch_bounds__(256) void fb_node3(const float2* __restrict__ g2, const float2* __restrict__ A2,
                                                const float* __restrict__ b2, const float* __restrict__ dinv,
                                                float2* __restrict__ out) {
    int i = blockIdx.x * 256 + threadIdx.x;
    if (i >= N_NODES) return;
    float di = dinv[i];
    float2 a = A2[i], g = g2[i];
    out[i] = make_float2(di * (a.x + g.x) + b2[0], di * (a.y + g.y) + b2[1]);
}

// ---------------- launcher ----------------

extern "C" void kernel_launch(void* const* d_in, const int* in_sizes, int n_in,
                              void* d_out, int out_size, void* d_ws, size_t ws_size,
                              hipStream_t stream) {
    const float* x  = (const float*)d_in[0];
    const float* W1 = (const float*)d_in[1];
    const float* b1 = (const float*)d_in[2];
    const float* W2 = (const float*)d_in[3];
    const float* b2 = (const float*)d_in[4];
    const int* ei   = (const int*)d_in[5];   // (2,E): row 0 = src, row 1 = dst
    const int* src = ei;
    const int* dst = ei + N_EDGES;
    float2* out = (float2*)d_out;

    // ws layout (4B words), same total as R5 (~61.6 MB):
    //   sorted      [E]                      12,800,000
    //   blockHist   [SORT_BLOCKS*K]           1,601,536  -- dead after scatter;
    //       reused for deg partials (3128*256 = 800,768 words) and
    //       agg partials (3128*512 = 1,601,536 words -- exact fit)
    //   bucketTotal [K]                             782
    //   bucketStart [K+1] (+1 pad)                  784
    //   dinv        [N]                         200,000
    //   u           [2N] (8B aligned)           400,000
    //   g2          [2N]                        400,000
    const size_t need = ((size_t)N_EDGES + (size_t)SORT_BLOCKS * K_BUCKETS + 782 + 784
                         + N_NODES + 2 * (size_t)N_NODES + 2 * (size_t)N_NODES) * 4;

    if (ws_size >= need) {
        unsigned* sorted      = (unsigned*)d_ws;
        unsigned* blockHist   = sorted + N_EDGES;
        unsigned* bucketTotal = blockHist + (size_t)SORT_BLOCKS * K_BUCKETS;
        unsigned* bucketStart = bucketTotal + 782;
        float*    dinv        = (float*)(bucketStart + 784);
        float2*   u           = (float2*)(dinv + N_NODES);
        float2*   g2          = u + N_NODES;
        unsigned* pcnt        = blockHist;            // deg partials (reuse)
        float2*   part        = (float2*)blockHist;   // agg partials (reuse)

        hist_kernel<<<SORT_BLOCKS, 256, 0, stream>>>(dst, blockHist);
        scan_perblock_kernel<<<K_BUCKETS, 256, 0, stream>>>(blockHist, bucketTotal);
        scan_buckets_kernel<<<1, 1024, 0, stream>>>(bucketTotal, bucketStart);
        scatter_kernel<<<SORT_BLOCKS, 256, 0, stream>>>(src, dst, blockHist, bucketStart, sorted);
        deg_part_kernel<<<K_BUCKETS * SEG, 256, 0, stream>>>(sorted, bucketStart, pcnt);
        node1_kernel<<<K_BUCKETS, 256, 0, stream>>>((const float2*)x, pcnt, dinv, u);
        agg_part_kernel<<<K_BUCKETS * SEG, 256, 0, stream>>>(sorted, bucketStart, u, part);
        node2_kernel<<<K_BUCKETS, 256, 0, stream>>>(u, part, W1, b1, W2, dinv, g2);
        agg_part_kernel<<<K_BUCKETS * SEG, 256, 0, stream>>>(sorted, bucketStart, g2, part);
        node3_kernel<<<K_BUCKETS, 256, 0, stream>>>(g2, part, b2, dinv, out);
    } else {
        // R2-style fallback (8 MB ws): global atomics, ~3.1 ms.
        float* ws = (float*)d_ws;
        int*   degi = (int*)ws;
        float* A1   = ws + N_NODES;
        float* A2   = A1 + 2 * (size_t)N_NODES;
        float* dinvF = A2 + 2 * (size_t)N_NODES;
        float2* uF  = (float2*)(dinvF + N_NODES);
        float2* g2F = uF + N_NODES;
        constexpr int EB = (N_EDGES + 255) / 256;
        constexpr int NB = (N_NODES + 255) / 256;
        hipMemsetAsync(degi, 0, 5 * (size_t)N_NODES * sizeof(float), stream);
        fb_deg<<<EB, 256, 0, stream>>>(dst, degi);
        fb_node1<<<NB, 256, 0, stream>>>(x, degi, dinvF, uF);
        fb_agg<<<EB, 256, 0, stream>>>(src, dst, uF, A1);
        fb_node2<<<NB, 256, 0, stream>>>(uF, (const float2*)A1, W1, b1, W2, dinvF, g2F);
        fb_agg<<<EB, 256, 0, stream>>>(src, dst, g2F, A2);
        fb_node3<<<NB, 256, 0, stream>>>(g2F, (const float2*)A2, b2, dinvF, out);
    }
}